// Round 10
// baseline (301.094 us; speedup 1.0000x reference)
//
#include <hip/hip_runtime.h>

// ---------------------------------------------------------------------------
// GIN 3-layer forward, MI355X (gfx950) — round 10
// Round 9 base + agg->GEMM fusion: each aggregation now writes its result
// tile directly into LDS (MFMA operand layout) and the consuming GEMM (or
// GEMM pair) runs in the same kernel. Eliminates 3x25.6MB round trips and 3
// launches. A-tile rows are wave-local through all phases (agg write, GEMM1
// read, Y1 rewrite, GEMM2 read) -> only B staging needs barriers.
// Dispatches: 15 -> 11.
// ---------------------------------------------------------------------------

typedef __bf16 bf16x8_t __attribute__((ext_vector_type(8)));
typedef float f32x4_t __attribute__((ext_vector_type(4)));
typedef unsigned short u16x8_t __attribute__((ext_vector_type(8)));
typedef unsigned short u16x4_t __attribute__((ext_vector_type(4)));

__device__ __forceinline__ unsigned short f2bf(float f) {
  unsigned u = __builtin_bit_cast(unsigned, f);
  u += 0x7FFFu + ((u >> 16) & 1u);
  return (unsigned short)(u >> 16);
}
__device__ __forceinline__ float bf2f(unsigned short h) {
  unsigned u = ((unsigned)h) << 16;
  return __builtin_bit_cast(float, u);
}

// ---------------- CSR build: 2-level counting sort ----------------
__global__ __launch_bounds__(256) void k_bcount(const int* __restrict__ dst,
                                                unsigned* __restrict__ tot,
                                                int E, int nb) {
  __shared__ unsigned c[256];
  c[threadIdx.x] = 0;
  __syncthreads();
  for (int e = blockIdx.x * 256 + threadIdx.x; e < E; e += gridDim.x * 256)
    atomicAdd(&c[dst[e] >> 8], 1u);
  __syncthreads();
  int t = threadIdx.x;
  if (t < nb && c[t]) atomicAdd(&tot[t], c[t]);
}

// also zeroes the stats buffer (runs before any stats accumulation)
__global__ void k_bscan(const unsigned* __restrict__ tot, unsigned* __restrict__ base,
                        unsigned* __restrict__ fill, float* __restrict__ stats, int nb) {
  __shared__ unsigned s[256];
  int t = threadIdx.x;
  for (int i = t; i < 1024; i += 256) stats[i] = 0.f;
  s[t] = (t < nb) ? tot[t] : 0u;
  __syncthreads();
  for (int o = 1; o < 256; o <<= 1) {
    unsigned u = (t >= o) ? s[t - o] : 0u;
    __syncthreads();
    s[t] += u;
    __syncthreads();
  }
  unsigned excl = t ? s[t - 1] : 0u;
  if (t < nb) {
    base[t] = excl;
    fill[t] = excl;
  }
  if (t == nb) base[t] = s[nb - 1];  // total = E
}

// pass 1: partition packed (dst_low<<24 | src) into bucket regions of ebuf.
__global__ __launch_bounds__(256) void k_bucket(const int* __restrict__ src,
                                                const int* __restrict__ dst,
                                                unsigned* __restrict__ bucket_fill,
                                                unsigned* __restrict__ ebuf,
                                                int E, int nb, int chunk) {
  __shared__ unsigned cntl[256];
  __shared__ unsigned basel[256];
  __shared__ unsigned fill2[256];
  const int t = threadIdx.x;
  cntl[t] = 0;
  fill2[t] = 0;
  __syncthreads();
  const int lo = blockIdx.x * chunk;
  const int hi = (lo + chunk < E) ? lo + chunk : E;
  for (int e = lo + t; e < hi; e += 256)
    atomicAdd(&cntl[dst[e] >> 8], 1u);
  __syncthreads();
  if (t < nb) basel[t] = atomicAdd(&bucket_fill[t], cntl[t]);
  __syncthreads();
  for (int e = lo + t; e < hi; e += 256) {
    int d = dst[e];
    int b = d >> 8;
    unsigned slot = atomicAdd(&fill2[b], 1u);
    ebuf[basel[b] + slot] = ((unsigned)(d & 255) << 24) | (unsigned)src[e];
  }
}

// pass 2: one block per bucket — histogram + scan + scatter within the
// bucket's contiguous (L2-resident) csr window; csr_off written coalesced.
__global__ __launch_bounds__(256) void k_build(const unsigned* __restrict__ ebuf,
                                               const unsigned* __restrict__ bucket_base,
                                               unsigned* __restrict__ csr_off,
                                               int* __restrict__ csr, int N) {
  __shared__ unsigned cntl[256];
  __shared__ unsigned scl[256];
  __shared__ unsigned startl[256];
  __shared__ unsigned filll[256];
  const int b = blockIdx.x;
  const int t = threadIdx.x;
  const unsigned ebeg = bucket_base[b];
  const unsigned eend = bucket_base[b + 1];
  cntl[t] = 0;
  filll[t] = 0;
  __syncthreads();
  for (unsigned e = ebeg + t; e < eend; e += 256)
    atomicAdd(&cntl[ebuf[e] >> 24], 1u);
  __syncthreads();
  unsigned v = cntl[t];
  scl[t] = v;
  __syncthreads();
  for (int o = 1; o < 256; o <<= 1) {
    unsigned u = (t >= o) ? scl[t - o] : 0u;
    __syncthreads();
    scl[t] += u;
    __syncthreads();
  }
  int node = b * 256 + t;
  if (node < N) csr_off[node] = ebeg + scl[t];  // inclusive (END) offsets
  startl[t] = scl[t] - v;                       // exclusive start
  __syncthreads();
  for (unsigned e = ebeg + t; e < eend; e += 256) {
    unsigned p = ebuf[e];
    unsigned d = p >> 24;
    unsigned slot = atomicAdd(&filll[d], 1u);
    csr[ebeg + startl[d] + slot] = (int)(p & 0xFFFFFFu);
  }
}

// ---------------- fused: weight transpose+bf16 (blocks 0..95) + x->bf16 ------
__global__ void k_wtx(const float* w0, const float* w1, const float* w2,
                      const float* w3, const float* w4, const float* w5,
                      unsigned short* __restrict__ wT,
                      const float* __restrict__ x, unsigned short* __restrict__ xb,
                      int total8) {
  if (blockIdx.x < 96) {
    const float* ws[6] = {w0, w1, w2, w3, w4, w5};
    int m = blockIdx.x >> 4;
    int tl = blockIdx.x & 15;
    int tr = (tl >> 2) * 32;
    int tc = (tl & 3) * 32;
    const float* W = ws[m];
    __shared__ float sm[32][33];
    int r = threadIdx.x >> 3;
    int c4 = (threadIdx.x & 7) * 4;
    float4 v = *reinterpret_cast<const float4*>(&W[(tr + r) * 128 + tc + c4]);
    sm[r][c4 + 0] = v.x; sm[r][c4 + 1] = v.y; sm[r][c4 + 2] = v.z; sm[r][c4 + 3] = v.w;
    __syncthreads();
    u16x4_t o;
    o[0] = f2bf(sm[c4 + 0][r]);
    o[1] = f2bf(sm[c4 + 1][r]);
    o[2] = f2bf(sm[c4 + 2][r]);
    o[3] = f2bf(sm[c4 + 3][r]);
    *reinterpret_cast<u16x4_t*>(&wT[(size_t)m * 16384 + (tc + r) * 128 + tr + c4]) = o;
  } else {
    int i = (blockIdx.x - 96) * 256 + threadIdx.x;
    if (i >= total8) return;
    const float* p = x + (size_t)i * 8;
    float4 f0 = *reinterpret_cast<const float4*>(p);
    float4 f1 = *reinterpret_cast<const float4*>(p + 4);
    u16x8_t o;
    o[0] = f2bf(f0.x); o[1] = f2bf(f0.y); o[2] = f2bf(f0.z); o[3] = f2bf(f0.w);
    o[4] = f2bf(f1.x); o[5] = f2bf(f1.y); o[6] = f2bf(f1.z); o[7] = f2bf(f1.w);
    *reinterpret_cast<u16x8_t*>(xb + (size_t)i * 8) = o;
  }
}

// ---------------- fused agg + GEMM(s) ----------------
// 512 threads = 8 waves; block covers 128 output rows; wave w owns rows
// w*16..w*16+15 through ALL phases (agg write -> GEMM1 A-read -> Y1 rewrite
// -> GEMM2 A-read), so Al needs no cross-wave barriers; only Bl staging does.
// MODE 0: plain agg (self from fp32 Zself). MODE 1: agg applies BN+ReLU from
// raw stats. PAIR=false: Y = agg@W1+b1 (+stats). PAIR=true:
// Y = relu(agg@W1+b1)@W2+b2 (+stats).
template<int MODE, bool PAIR>
__global__ __launch_bounds__(512, 4) void k_fused(
    const unsigned short* __restrict__ Zv, const float* __restrict__ Zself,
    const float* __restrict__ ssum, const float* __restrict__ ssq,
    const float* __restrict__ gg, const float* __restrict__ bb,
    const int* __restrict__ csr, const unsigned* __restrict__ offend,
    const float* __restrict__ epsp,
    const unsigned short* __restrict__ BT1, const float* __restrict__ bias1,
    const unsigned short* __restrict__ BT2, const float* __restrict__ bias2,
    unsigned short* __restrict__ Y, float* __restrict__ osum, float* __restrict__ osq,
    int M, int N) {
  __shared__ __attribute__((aligned(16))) unsigned short Al[128][136];  // agg out, then Y1
  __shared__ __attribute__((aligned(16))) unsigned short Bl[128][136];  // W1, then W2
  __shared__ float cs[128], cq[128];
  __shared__ float scl[128], shl[128];
  const int tid = threadIdx.x;
  const int r0 = blockIdx.x * 128;
  const int trow = tid >> 4;       // 0..31
  const int tch = (tid & 15) * 8;

  // stage W1 -> Bl
#pragma unroll
  for (int pass = 0; pass < 4; ++pass) {
    int n = pass * 32 + trow;
    *reinterpret_cast<u16x8_t*>(&Bl[n][tch]) =
        *reinterpret_cast<const u16x8_t*>(&BT1[(size_t)n * 128 + tch]);
  }
  if (MODE == 1 && tid < 128) {
    float inv = 1.f / (float)N;
    float m = ssum[tid] * inv;
    float vv = ssq[tid] * inv - m * m;
    float s = gg[tid] * rsqrtf(vv + 1e-5f);
    scl[tid] = s;
    shl[tid] = bb[tid] - m * s;
  }
  if (tid < 128) { cs[tid] = 0.f; cq[tid] = 0.f; }
  if (MODE == 1) __syncthreads();  // scl/shl needed by agg phase

  const int wave = tid >> 6;       // 0..7
  const int lane = tid & 63;
  const int sub = lane >> 4;       // 0..3 (agg subgroup / GEMM k-group)
  const int lr = lane & 15;        // agg channel-slice / GEMM row-in-tile
  const int c0 = lr * 8;
  const int lkb = sub * 8;

  float sc[8], sh[8];
  if (MODE == 1) {
#pragma unroll
    for (int j = 0; j < 8; ++j) { sc[j] = scl[c0 + j]; sh[j] = shl[c0 + j]; }
  }
  const float ep = 1.f + epsp[0];

  // ---- agg phase: wave w aggregates its 16 rows into Al ----
  for (int i16 = 0; i16 < 16; ++i16) {
    const int row = wave * 16 + i16;
    const int node = r0 + row;
    if (node >= N) break;  // wave-uniform

    float s[8];
#pragma unroll
    for (int j = 0; j < 8; ++j) s[j] = 0.f;

    auto accum = [&](int rw) {
      u16x8_t v = *reinterpret_cast<const u16x8_t*>(Zv + (size_t)rw * 128 + c0);
      if (MODE == 0) {
#pragma unroll
        for (int j = 0; j < 8; ++j) s[j] += bf2f(v[j]);
      } else {
#pragma unroll
        for (int j = 0; j < 8; ++j) s[j] += fmaxf(bf2f(v[j]) * sc[j] + sh[j], 0.f);
      }
    };

    const unsigned beg = node ? offend[node - 1] : 0u;
    const unsigned end = offend[node];
    const int deg = (int)(end - beg);
    const int deg64 = deg < 64 ? deg : 64;

    int idx = (lane < deg64) ? csr[beg + lane] : 0;

    const int nIter = (deg64 + 3) >> 2;
    int p = sub;
    int i = 0;
    for (; i + 4 <= nIter; i += 4, p += 16) {
      int rw0 = __shfl(idx, p);
      int rw1 = __shfl(idx, p + 4);
      int rw2 = __shfl(idx, p + 8);
      int rw3 = __shfl(idx, p + 12);
      if (p < deg64) accum(rw0);
      if (p + 4 < deg64) accum(rw1);
      if (p + 8 < deg64) accum(rw2);
      if (p + 12 < deg64) accum(rw3);
    }
    for (; i < nIter; ++i, p += 4) {
      int rw0 = __shfl(idx, p);
      if (p < deg64) accum(rw0);
    }
    for (int e = 64 + sub; e < deg; e += 4) accum(csr[beg + e]);

    if (sub == 0) {
      if (MODE == 0) {
        const float* Z = Zself + (size_t)node * 128 + c0;
        float4 f0 = *reinterpret_cast<const float4*>(Z);
        float4 f1 = *reinterpret_cast<const float4*>(Z + 4);
        s[0] += ep * f0.x; s[1] += ep * f0.y; s[2] += ep * f0.z; s[3] += ep * f0.w;
        s[4] += ep * f1.x; s[5] += ep * f1.y; s[6] += ep * f1.z; s[7] += ep * f1.w;
      } else {
        u16x8_t v = *reinterpret_cast<const u16x8_t*>(Zv + (size_t)node * 128 + c0);
#pragma unroll
        for (int j = 0; j < 8; ++j)
          s[j] += ep * fmaxf(bf2f(v[j]) * sc[j] + sh[j], 0.f);
      }
    }

#pragma unroll
    for (int j = 0; j < 8; ++j) {
      s[j] += __shfl_xor(s[j], 16);
      s[j] += __shfl_xor(s[j], 32);
    }

    if (sub == 0) {
      u16x8_t o;
#pragma unroll
      for (int j = 0; j < 8; ++j) o[j] = f2bf(s[j]);
      *reinterpret_cast<u16x8_t*>(&Al[row][c0]) = o;
    }
  }
  __syncthreads();  // Bl(W1) visible to all; Al rows are wave-local

  // ---- GEMM1: wave's 16 rows ----
  u16x8_t araw[4];
#pragma unroll
  for (int kc = 0; kc < 4; ++kc)
    araw[kc] = *reinterpret_cast<const u16x8_t*>(&Al[wave * 16 + lr][kc * 32 + lkb]);

  f32x4_t acc[8];
  f32x4_t zero = {0.f, 0.f, 0.f, 0.f};
#pragma unroll
  for (int i = 0; i < 8; ++i) acc[i] = zero;

#pragma unroll
  for (int kc = 0; kc < 4; ++kc) {
    bf16x8_t af = __builtin_bit_cast(bf16x8_t, araw[kc]);
#pragma unroll
    for (int nt = 0; nt < 8; ++nt) {
      bf16x8_t bf = __builtin_bit_cast(bf16x8_t,
          *reinterpret_cast<const u16x8_t*>(&Bl[nt * 16 + lr][kc * 32 + lkb]));
      acc[nt] = __builtin_amdgcn_mfma_f32_16x16x32_bf16(af, bf, acc[nt], 0, 0, 0);
    }
  }

  const int g = lane >> 4;
  if (PAIR) {
    __syncthreads();  // all waves done reading Bl(W1)
    // W2 -> Bl
#pragma unroll
    for (int pass = 0; pass < 4; ++pass) {
      int n = pass * 32 + trow;
      *reinterpret_cast<u16x8_t*>(&Bl[n][tch]) =
          *reinterpret_cast<const u16x8_t*>(&BT2[(size_t)n * 128 + tch]);
    }
    // Y1 = relu(acc + b1) -> Al (wave-local rows)
#pragma unroll
    for (int nt = 0; nt < 8; ++nt) {
      int col = nt * 16 + lr;
      float bv = bias1[col];
#pragma unroll
      for (int j = 0; j < 4; ++j)
        Al[wave * 16 + g * 4 + j][col] = f2bf(fmaxf(acc[nt][j] + bv, 0.f));
    }
    __syncthreads();  // Bl(W2) ready

    // GEMM2
#pragma unroll
    for (int kc = 0; kc < 4; ++kc)
      araw[kc] = *reinterpret_cast<const u16x8_t*>(&Al[wave * 16 + lr][kc * 32 + lkb]);
#pragma unroll
    for (int i = 0; i < 8; ++i) acc[i] = zero;
#pragma unroll
    for (int kc = 0; kc < 4; ++kc) {
      bf16x8_t af = __builtin_bit_cast(bf16x8_t, araw[kc]);
#pragma unroll
      for (int nt = 0; nt < 8; ++nt) {
        bf16x8_t bf = __builtin_bit_cast(bf16x8_t,
            *reinterpret_cast<const u16x8_t*>(&Bl[nt * 16 + lr][kc * 32 + lkb]));
        acc[nt] = __builtin_amdgcn_mfma_f32_16x16x32_bf16(af, bf, acc[nt], 0, 0, 0);
      }
    }
  }

  // ---- epilogue + stats ----
  const float* bias = PAIR ? bias2 : bias1;
#pragma unroll
  for (int nt = 0; nt < 8; ++nt) {
    int col = nt * 16 + lr;
    float bv = bias[col];
    float s4 = 0.f, q4 = 0.f;
#pragma unroll
    for (int j = 0; j < 4; ++j) {
      int gr = r0 + wave * 16 + g * 4 + j;
      float v = acc[nt][j] + bv;
      if (gr < M) {
        Y[(size_t)gr * 128 + col] = f2bf(v);
        s4 += v; q4 += v * v;
      }
    }
    s4 += __shfl_xor(s4, 16);
    s4 += __shfl_xor(s4, 32);
    q4 += __shfl_xor(q4, 16);
    q4 += __shfl_xor(q4, 32);
    if (lane < 16) { atomicAdd(&cs[col], s4); atomicAdd(&cq[col], q4); }
  }
  __syncthreads();
  if (tid < 128) {
    atomicAdd(&osum[tid], cs[tid]);
    atomicAdd(&osq[tid], cq[tid]);
  }
}

// ---------------- single GEMM: Y = bn_relu(A) @ W + bias, + stats ------------
// (standalone, used for layer-0 second linear) — round-9 form.
__global__ __launch_bounds__(256) void k_mm(
    const unsigned short* __restrict__ A,
    const float* __restrict__ ssum, const float* __restrict__ ssq,
    const float* __restrict__ gg, const float* __restrict__ bb,
    const unsigned short* __restrict__ BT, const float* __restrict__ bias,
    unsigned short* __restrict__ Y, float* __restrict__ osum, float* __restrict__ osq,
    int M, int N) {
  __shared__ __attribute__((aligned(16))) unsigned short Bl[128][136];
  __shared__ float cs[128], cq[128];
  __shared__ float scl[128], shl[128];
  const int tid = threadIdx.x;
  const int r0 = blockIdx.x * 128;
  const int trow = tid >> 4;
  const int tch = (tid & 15) * 8;

#pragma unroll
  for (int pass = 0; pass < 8; ++pass) {
    int n = pass * 16 + trow;
    u16x8_t v = *reinterpret_cast<const u16x8_t*>(&BT[(size_t)n * 128 + tch]);
    *reinterpret_cast<u16x8_t*>(&Bl[n][tch]) = v;
  }
  if (tid < 128) {
    float inv = 1.f / (float)N;
    float m = ssum[tid] * inv;
    float vv = ssq[tid] * inv - m * m;
    float s = gg[tid] * rsqrtf(vv + 1e-5f);
    scl[tid] = s;
    shl[tid] = bb[tid] - m * s;
    cs[tid] = 0.f; cq[tid] = 0.f;
  }

  const int wave = tid >> 6;
  const int lane = tid & 63;
  const int lr = lane & 15;
  const int lkb = (lane >> 4) * 8;
  const int wr = r0 + wave * 32;

  u16x8_t araw[2][4];
  const u16x8_t zv = {0, 0, 0, 0, 0, 0, 0, 0};
#pragma unroll
  for (int mr = 0; mr < 2; ++mr) {
    int grow = wr + mr * 16 + lr;
    bool ok = grow < M;
    const unsigned short* Ar = A + (size_t)grow * 128 + lkb;
#pragma unroll
    for (int kc = 0; kc < 4; ++kc)
      araw[mr][kc] = ok ? *reinterpret_cast<const u16x8_t*>(Ar + kc * 32) : zv;
  }
  __syncthreads();

  // BN + ReLU on A fragments
#pragma unroll
  for (int kc = 0; kc < 4; ++kc) {
    float scv[8], shv[8];
#pragma unroll
    for (int j = 0; j < 8; ++j) {
      int c = kc * 32 + lkb + j;
      scv[j] = scl[c]; shv[j] = shl[c];
    }
#pragma unroll
    for (int mr = 0; mr < 2; ++mr) {
#pragma unroll
      for (int j = 0; j < 8; ++j)
        araw[mr][kc][j] = f2bf(fmaxf(bf2f(araw[mr][kc][j]) * scv[j] + shv[j], 0.f));
    }
  }

  f32x4_t acc[2][8];
  f32x4_t zero = {0.f, 0.f, 0.f, 0.f};
#pragma unroll
  for (int mr = 0; mr < 2; ++mr)
#pragma unroll
    for (int i = 0; i < 8; ++i) acc[mr][i] = zero;

#pragma unroll
  for (int kc = 0; kc < 4; ++kc) {
    bf16x8_t a0 = __builtin_bit_cast(bf16x8_t, araw[0][kc]);
    bf16x8_t a1 = __builtin_bit_cast(bf16x8_t, araw[1][kc]);
#pragma unroll
    for (int nt = 0; nt < 8; ++nt) {
      bf16x8_t bf = __builtin_bit_cast(bf16x8_t,
          *reinterpret_cast<const u16x8_t*>(&Bl[nt * 16 + lr][kc * 32 + lkb]));
      acc[0][nt] = __builtin_amdgcn_mfma_f32_16x16x32_bf16(a0, bf, acc[0][nt], 0, 0, 0);
      acc[1][nt] = __builtin_amdgcn_mfma_f32_16x16x32_bf16(a1, bf, acc[1][nt], 0, 0, 0);
    }
  }

  const int g = lane >> 4;
#pragma unroll
  for (int mr = 0; mr < 2; ++mr) {
#pragma unroll
    for (int nt = 0; nt < 8; ++nt) {
      int col = nt * 16 + lr;
      float bv = bias[col];
      float s4 = 0.f, q4 = 0.f;
#pragma unroll
      for (int j = 0; j < 4; ++j) {
        int gr = wr + mr * 16 + g * 4 + j;
        float v = acc[mr][nt][j] + bv;
        if (gr < M) {
          Y[(size_t)gr * 128 + col] = f2bf(v);
          s4 += v; q4 += v * v;
        }
      }
      s4 += __shfl_xor(s4, 16);
      s4 += __shfl_xor(s4, 32);
      q4 += __shfl_xor(q4, 16);
      q4 += __shfl_xor(q4, 32);
      if (lane < 16) { atomicAdd(&cs[col], s4); atomicAdd(&cq[col], q4); }
    }
  }
  __syncthreads();
  if (tid < 128) {
    atomicAdd(&osum[tid], cs[tid]);
    atomicAdd(&osq[tid], cq[tid]);
  }
}

// ---------------- final: out = relu(bn(Y)) as fp32 ---------------------------
__global__ void k_final(const unsigned short* __restrict__ Y,
                        const float* __restrict__ ssum, const float* __restrict__ ssq,
                        const float* __restrict__ gg, const float* __restrict__ bb,
                        float* __restrict__ out, int total8, int N) {
  __shared__ float scl[128], shl[128];
  const int tid = threadIdx.x;
  if (tid < 128) {
    float inv = 1.f / (float)N;
    float m = ssum[tid] * inv;
    float vv = ssq[tid] * inv - m * m;
    float s = gg[tid] * rsqrtf(vv + 1e-5f);
    scl[tid] = s;
    shl[tid] = bb[tid] - m * s;
  }
  __syncthreads();
  int i = blockIdx.x * 256 + tid;
  if (i >= total8) return;
  int base = i * 8;
  int c = base & 127;
  u16x8_t v = *reinterpret_cast<const u16x8_t*>(&Y[base]);
  float4 o0, o1;
  o0.x = fmaxf(bf2f(v[0]) * scl[c + 0] + shl[c + 0], 0.f);
  o0.y = fmaxf(bf2f(v[1]) * scl[c + 1] + shl[c + 1], 0.f);
  o0.z = fmaxf(bf2f(v[2]) * scl[c + 2] + shl[c + 2], 0.f);
  o0.w = fmaxf(bf2f(v[3]) * scl[c + 3] + shl[c + 3], 0.f);
  o1.x = fmaxf(bf2f(v[4]) * scl[c + 4] + shl[c + 4], 0.f);
  o1.y = fmaxf(bf2f(v[5]) * scl[c + 5] + shl[c + 5], 0.f);
  o1.z = fmaxf(bf2f(v[6]) * scl[c + 6] + shl[c + 6], 0.f);
  o1.w = fmaxf(bf2f(v[7]) * scl[c + 7] + shl[c + 7], 0.f);
  *reinterpret_cast<float4*>(&out[base]) = o0;
  *reinterpret_cast<float4*>(&out[base + 4]) = o1;
}

// ---------------------------------------------------------------------------
extern "C" void kernel_launch(void* const* d_in, const int* in_sizes, int n_in,
                              void* d_out, int out_size, void* d_ws, size_t ws_size,
                              hipStream_t stream) {
  (void)n_in; (void)out_size; (void)ws_size;
  const float* x = (const float*)d_in[0];
  const int* ei = (const int*)d_in[1];
  const float* eps = (const float*)d_in[2];
  const int N = in_sizes[0] / 128;
  const int E = in_sizes[1] / 2;
  const int* src = ei;
  const int* dst = ei + E;

  char* ws = (char*)d_ws;
  size_t off = 0;
  auto alloc = [&](size_t bytes) -> char* {
    char* p = ws + off;
    off += (bytes + 255) & ~(size_t)255;
    return p;
  };
  unsigned* csr_off = (unsigned*)alloc((size_t)N * 4);
  int* csr_src = (int*)alloc((size_t)E * 4);
  unsigned* bucket_tot = (unsigned*)alloc(256 * 4);
  unsigned* bucket_base = (unsigned*)alloc(257 * 4);
  unsigned* bucket_fill = (unsigned*)alloc(256 * 4);
  float* stats = (float*)alloc(8 * 128 * 4);   // 4x (sum,sq)
  unsigned short* wT = (unsigned short*)alloc(6 * 128 * 128 * 2);
  unsigned short* xb = (unsigned short*)alloc((size_t)N * 128 * 2);
  unsigned short* B1 = (unsigned short*)alloc((size_t)N * 128 * 2);
  unsigned short* B2 = (unsigned short*)alloc((size_t)N * 128 * 2);
  // ebuf aliases B1: dead once k_build completes; first B1 write is k_mm out.
  unsigned* ebuf = (unsigned*)B1;

  hipMemsetAsync(bucket_tot, 0, 256 * 4, stream);

  const int NBUCK = (N + 255) >> 8;            // 196 for N=50000 (<= 256)
  const int gM = (N + 127) / 128;
  const int gF = ((N * 128 / 8) + 255) / 256;
  const int chunk = (E + 255) / 256;

  k_bcount<<<256, 256, 0, stream>>>(dst, bucket_tot, E, NBUCK);
  k_bscan<<<1, 256, 0, stream>>>(bucket_tot, bucket_base, bucket_fill, stats, NBUCK);
  k_bucket<<<256, 256, 0, stream>>>(src, dst, bucket_fill, ebuf, E, NBUCK, chunk);
  k_build<<<NBUCK, 256, 0, stream>>>(ebuf, bucket_base, csr_off, csr_src, N);
  k_wtx<<<96 + gF, 256, 0, stream>>>((const float*)d_in[3], (const float*)d_in[7],
                                     (const float*)d_in[11], (const float*)d_in[13],
                                     (const float*)d_in[17], (const float*)d_in[19], wT,
                                     x, xb, N * 128 / 8);

  // Layer 0: fused agg0+mm1(+stats s0) -> mm2(bn0-in, +stats s1)
  k_fused<0, false><<<gM, 512, 0, stream>>>(xb, x, nullptr, nullptr, nullptr, nullptr,
      csr_src, csr_off, eps, wT + 0 * 16384, (const float*)d_in[4], nullptr, nullptr,
      B2, stats + 0, stats + 128, N, N);
  k_mm<<<gM, 256, 0, stream>>>(B2, stats + 0, stats + 128,
      (const float*)d_in[5], (const float*)d_in[6],
      wT + 1 * 16384, (const float*)d_in[8], B1, stats + 256, stats + 384, N, N);

  // Layer 1: fused agg1(bn1-in from s1)+pair (+stats s2)
  k_fused<1, true><<<gM, 512, 0, stream>>>(B1, nullptr, stats + 256, stats + 384,
      (const float*)d_in[9], (const float*)d_in[10],
      csr_src, csr_off, eps, wT + 2 * 16384, (const float*)d_in[12],
      wT + 3 * 16384, (const float*)d_in[14], B2, stats + 512, stats + 640, N, N);

  // Layer 2: fused agg2(bn2-in from s2)+pair (+stats s3)
  k_fused<1, true><<<gM, 512, 0, stream>>>(B2, nullptr, stats + 512, stats + 640,
      (const float*)d_in[15], (const float*)d_in[16],
      csr_src, csr_off, eps, wT + 4 * 16384, (const float*)d_in[18],
      wT + 5 * 16384, (const float*)d_in[20], B1, stats + 768, stats + 896, N, N);

  k_final<<<gF, 256, 0, stream>>>(B1, stats + 768, stats + 896,
                                  (const float*)d_in[21], (const float*)d_in[22],
                                  (float*)d_out, N * 128 / 8, N);
}

// Round 11
// 264.634 us; speedup vs baseline: 1.1378x; 1.1378x over previous
//
#include <hip/hip_runtime.h>

// ---------------------------------------------------------------------------
// GIN 3-layer forward, MI355X (gfx950) — round 11
// Round 9 base (fusion reverted: it halved agg occupancy, 77us vs 58us).
// Deltas: (1) GEMM kernels go 256->512 threads, 16 rows/wave (2x wave
// parallelism; k_mm ~100% occupancy, mm2x 25%->50%) — they were latency-bound
// at 1.5 waves/SIMD; (2) csr indices stored u16 (N<65536): halves csr
// traffic in k_build + all three aggs.
// ---------------------------------------------------------------------------

typedef __bf16 bf16x8_t __attribute__((ext_vector_type(8)));
typedef float f32x4_t __attribute__((ext_vector_type(4)));
typedef unsigned short u16x8_t __attribute__((ext_vector_type(8)));
typedef unsigned short u16x4_t __attribute__((ext_vector_type(4)));

__device__ __forceinline__ unsigned short f2bf(float f) {
  unsigned u = __builtin_bit_cast(unsigned, f);
  u += 0x7FFFu + ((u >> 16) & 1u);
  return (unsigned short)(u >> 16);
}
__device__ __forceinline__ float bf2f(unsigned short h) {
  unsigned u = ((unsigned)h) << 16;
  return __builtin_bit_cast(float, u);
}

// ---------------- CSR build: 2-level counting sort ----------------
__global__ __launch_bounds__(256) void k_bcount(const int* __restrict__ dst,
                                                unsigned* __restrict__ tot,
                                                int E, int nb) {
  __shared__ unsigned c[256];
  c[threadIdx.x] = 0;
  __syncthreads();
  for (int e = blockIdx.x * 256 + threadIdx.x; e < E; e += gridDim.x * 256)
    atomicAdd(&c[dst[e] >> 8], 1u);
  __syncthreads();
  int t = threadIdx.x;
  if (t < nb && c[t]) atomicAdd(&tot[t], c[t]);
}

// also zeroes the stats buffer (runs before any stats accumulation)
__global__ void k_bscan(const unsigned* __restrict__ tot, unsigned* __restrict__ base,
                        unsigned* __restrict__ fill, float* __restrict__ stats, int nb) {
  __shared__ unsigned s[256];
  int t = threadIdx.x;
  for (int i = t; i < 1024; i += 256) stats[i] = 0.f;
  s[t] = (t < nb) ? tot[t] : 0u;
  __syncthreads();
  for (int o = 1; o < 256; o <<= 1) {
    unsigned u = (t >= o) ? s[t - o] : 0u;
    __syncthreads();
    s[t] += u;
    __syncthreads();
  }
  unsigned excl = t ? s[t - 1] : 0u;
  if (t < nb) {
    base[t] = excl;
    fill[t] = excl;
  }
  if (t == nb) base[t] = s[nb - 1];  // total = E
}

// pass 1: partition packed (dst_low<<24 | src) into bucket regions of ebuf.
__global__ __launch_bounds__(256) void k_bucket(const int* __restrict__ src,
                                                const int* __restrict__ dst,
                                                unsigned* __restrict__ bucket_fill,
                                                unsigned* __restrict__ ebuf,
                                                int E, int nb, int chunk) {
  __shared__ unsigned cntl[256];
  __shared__ unsigned basel[256];
  __shared__ unsigned fill2[256];
  const int t = threadIdx.x;
  cntl[t] = 0;
  fill2[t] = 0;
  __syncthreads();
  const int lo = blockIdx.x * chunk;
  const int hi = (lo + chunk < E) ? lo + chunk : E;
  for (int e = lo + t; e < hi; e += 256)
    atomicAdd(&cntl[dst[e] >> 8], 1u);
  __syncthreads();
  if (t < nb) basel[t] = atomicAdd(&bucket_fill[t], cntl[t]);
  __syncthreads();
  for (int e = lo + t; e < hi; e += 256) {
    int d = dst[e];
    int b = d >> 8;
    unsigned slot = atomicAdd(&fill2[b], 1u);
    ebuf[basel[b] + slot] = ((unsigned)(d & 255) << 24) | (unsigned)src[e];
  }
}

// pass 2: one block per bucket — histogram + scan + scatter within the
// bucket's contiguous (L2-resident) csr window; csr_off written coalesced.
// csr stored as u16 (node ids < 65536).
__global__ __launch_bounds__(256) void k_build(const unsigned* __restrict__ ebuf,
                                               const unsigned* __restrict__ bucket_base,
                                               unsigned* __restrict__ csr_off,
                                               unsigned short* __restrict__ csr, int N) {
  __shared__ unsigned cntl[256];
  __shared__ unsigned scl[256];
  __shared__ unsigned startl[256];
  __shared__ unsigned filll[256];
  const int b = blockIdx.x;
  const int t = threadIdx.x;
  const unsigned ebeg = bucket_base[b];
  const unsigned eend = bucket_base[b + 1];
  cntl[t] = 0;
  filll[t] = 0;
  __syncthreads();
  for (unsigned e = ebeg + t; e < eend; e += 256)
    atomicAdd(&cntl[ebuf[e] >> 24], 1u);
  __syncthreads();
  unsigned v = cntl[t];
  scl[t] = v;
  __syncthreads();
  for (int o = 1; o < 256; o <<= 1) {
    unsigned u = (t >= o) ? scl[t - o] : 0u;
    __syncthreads();
    scl[t] += u;
    __syncthreads();
  }
  int node = b * 256 + t;
  if (node < N) csr_off[node] = ebeg + scl[t];  // inclusive (END) offsets
  startl[t] = scl[t] - v;                       // exclusive start
  __syncthreads();
  for (unsigned e = ebeg + t; e < eend; e += 256) {
    unsigned p = ebuf[e];
    unsigned d = p >> 24;
    unsigned slot = atomicAdd(&filll[d], 1u);
    csr[ebeg + startl[d] + slot] = (unsigned short)(p & 0xFFFFu);
  }
}

// ---------------- fused: weight transpose+bf16 (blocks 0..95) + x->bf16 ------
__global__ void k_wtx(const float* w0, const float* w1, const float* w2,
                      const float* w3, const float* w4, const float* w5,
                      unsigned short* __restrict__ wT,
                      const float* __restrict__ x, unsigned short* __restrict__ xb,
                      int total8) {
  if (blockIdx.x < 96) {
    const float* ws[6] = {w0, w1, w2, w3, w4, w5};
    int m = blockIdx.x >> 4;
    int tl = blockIdx.x & 15;
    int tr = (tl >> 2) * 32;
    int tc = (tl & 3) * 32;
    const float* W = ws[m];
    __shared__ float sm[32][33];
    int r = threadIdx.x >> 3;
    int c4 = (threadIdx.x & 7) * 4;
    float4 v = *reinterpret_cast<const float4*>(&W[(tr + r) * 128 + tc + c4]);
    sm[r][c4 + 0] = v.x; sm[r][c4 + 1] = v.y; sm[r][c4 + 2] = v.z; sm[r][c4 + 3] = v.w;
    __syncthreads();
    u16x4_t o;
    o[0] = f2bf(sm[c4 + 0][r]);
    o[1] = f2bf(sm[c4 + 1][r]);
    o[2] = f2bf(sm[c4 + 2][r]);
    o[3] = f2bf(sm[c4 + 3][r]);
    *reinterpret_cast<u16x4_t*>(&wT[(size_t)m * 16384 + (tc + r) * 128 + tr + c4]) = o;
  } else {
    int i = (blockIdx.x - 96) * 256 + threadIdx.x;
    if (i >= total8) return;
    const float* p = x + (size_t)i * 8;
    float4 f0 = *reinterpret_cast<const float4*>(p);
    float4 f1 = *reinterpret_cast<const float4*>(p + 4);
    u16x8_t o;
    o[0] = f2bf(f0.x); o[1] = f2bf(f0.y); o[2] = f2bf(f0.z); o[3] = f2bf(f0.w);
    o[4] = f2bf(f1.x); o[5] = f2bf(f1.y); o[6] = f2bf(f1.z); o[7] = f2bf(f1.w);
    *reinterpret_cast<u16x8_t*>(xb + (size_t)i * 8) = o;
  }
}

// ---------------- aggregation (round-9 form, u16 csr) ----------------
// One wave per node; 4 subgroups x 16 lanes; lane covers 8 channels (16B).
// Exec-convergent shuffle loop (trip count wave-uniform, accum predicated).
// MODE 0: plain gather, self from fp32 Zself. MODE 1: folded BN affine+relu.
template<int MODE>
__global__ __launch_bounds__(256) void k_agg(
    const unsigned short* __restrict__ Zv, const float* __restrict__ Zself,
    const float* __restrict__ ssum, const float* __restrict__ ssq,
    const float* __restrict__ gg, const float* __restrict__ bb,
    const unsigned short* __restrict__ csr, const unsigned* __restrict__ offend,
    const float* __restrict__ epsp, unsigned short* __restrict__ out, int N) {
  __shared__ float scl[128], shl[128];
  const int tid = threadIdx.x;
  if (MODE == 1) {
    if (tid < 128) {
      float inv = 1.f / (float)N;
      float m = ssum[tid] * inv;
      float vv = ssq[tid] * inv - m * m;
      float s = gg[tid] * rsqrtf(vv + 1e-5f);
      scl[tid] = s;
      shl[tid] = bb[tid] - m * s;
    }
    __syncthreads();
  }
  int node = blockIdx.x * 4 + (tid >> 6);
  if (node >= N) return;
  const int lane = tid & 63;
  const int sub = lane >> 4;
  const int t = lane & 15;
  const int c0 = t * 8;

  float sc[8], sh[8];
  if (MODE == 1) {
#pragma unroll
    for (int j = 0; j < 8; ++j) { sc[j] = scl[c0 + j]; sh[j] = shl[c0 + j]; }
  }

  float s[8];
#pragma unroll
  for (int j = 0; j < 8; ++j) s[j] = 0.f;

  auto accum = [&](int row) {
    u16x8_t v = *reinterpret_cast<const u16x8_t*>(Zv + (size_t)row * 128 + c0);
    if (MODE == 0) {
#pragma unroll
      for (int j = 0; j < 8; ++j) s[j] += bf2f(v[j]);
    } else {
#pragma unroll
      for (int j = 0; j < 8; ++j) s[j] += fmaxf(bf2f(v[j]) * sc[j] + sh[j], 0.f);
    }
  };

  const unsigned beg = node ? offend[node - 1] : 0u;
  const unsigned end = offend[node];
  const int deg = (int)(end - beg);
  const int deg64 = deg < 64 ? deg : 64;

  int idx = (lane < deg64) ? (int)csr[beg + lane] : 0;

  // convergent shuffle loop, 4-deep: 4 rows in flight per subgroup
  const int nIter = (deg64 + 3) >> 2;
  int p = sub;
  int i = 0;
  for (; i + 4 <= nIter; i += 4, p += 16) {
    int r0 = __shfl(idx, p);
    int r1 = __shfl(idx, p + 4);
    int r2 = __shfl(idx, p + 8);
    int r3 = __shfl(idx, p + 12);
    if (p < deg64) accum(r0);
    if (p + 4 < deg64) accum(r1);
    if (p + 8 < deg64) accum(r2);
    if (p + 12 < deg64) accum(r3);
  }
  for (; i < nIter; ++i, p += 4) {
    int r0 = __shfl(idx, p);
    if (p < deg64) accum(r0);
  }

  // rare tail: degree > 64
  for (int e = 64 + sub; e < deg; e += 4) accum((int)csr[beg + e]);

  // self term, subgroup 0 only
  if (sub == 0) {
    float ep = 1.f + epsp[0];
    if (MODE == 0) {
      const float* Z = Zself + (size_t)node * 128 + c0;
      float4 f0 = *reinterpret_cast<const float4*>(Z);
      float4 f1 = *reinterpret_cast<const float4*>(Z + 4);
      s[0] += ep * f0.x; s[1] += ep * f0.y; s[2] += ep * f0.z; s[3] += ep * f0.w;
      s[4] += ep * f1.x; s[5] += ep * f1.y; s[6] += ep * f1.z; s[7] += ep * f1.w;
    } else {
      u16x8_t v = *reinterpret_cast<const u16x8_t*>(Zv + (size_t)node * 128 + c0);
#pragma unroll
      for (int j = 0; j < 8; ++j)
        s[j] += ep * fmaxf(bf2f(v[j]) * sc[j] + sh[j], 0.f);
    }
  }

  // reduce across the 4 subgroups (full-wave convergent)
#pragma unroll
  for (int j = 0; j < 8; ++j) {
    s[j] += __shfl_xor(s[j], 16);
    s[j] += __shfl_xor(s[j], 32);
  }

  if (sub == 0) {
    u16x8_t o;
#pragma unroll
    for (int j = 0; j < 8; ++j) o[j] = f2bf(s[j]);
    *reinterpret_cast<u16x8_t*>(out + (size_t)node * 128 + c0) = o;
  }
}

// ---------------- single GEMM: Y = transform(A) @ W + bias -------------------
// 512 threads, 8 waves, 16 rows/wave (128-row blocks): 2x wave parallelism vs
// round 9; Bl-only LDS (~37KB) -> ~4 blocks/CU. A direct global->register.
template<bool IN_BN, bool OUT_RELU, bool STATS>
__global__ __launch_bounds__(512) void k_mm(
    const unsigned short* __restrict__ A,
    const float* __restrict__ ssum, const float* __restrict__ ssq,
    const float* __restrict__ gg, const float* __restrict__ bb,
    const unsigned short* __restrict__ BT, const float* __restrict__ bias,
    unsigned short* __restrict__ Y, float* __restrict__ osum, float* __restrict__ osq,
    int M, int N) {
  __shared__ __attribute__((aligned(16))) unsigned short Bl[128][136];
  __shared__ float cs[128], cq[128];
  __shared__ float scl[128], shl[128];
  const int tid = threadIdx.x;
  const int r0 = blockIdx.x * 128;
  const int trow = tid >> 4;       // 0..31
  const int tch = (tid & 15) * 8;

#pragma unroll
  for (int pass = 0; pass < 4; ++pass) {
    int n = pass * 32 + trow;
    *reinterpret_cast<u16x8_t*>(&Bl[n][tch]) =
        *reinterpret_cast<const u16x8_t*>(&BT[(size_t)n * 128 + tch]);
  }
  if (IN_BN && tid < 128) {
    float inv = 1.f / (float)N;
    float m = ssum[tid] * inv;
    float vv = ssq[tid] * inv - m * m;
    float s = gg[tid] * rsqrtf(vv + 1e-5f);
    scl[tid] = s;
    shl[tid] = bb[tid] - m * s;
  }
  if (STATS && tid < 128) { cs[tid] = 0.f; cq[tid] = 0.f; }

  const int wave = tid >> 6;       // 0..7
  const int lane = tid & 63;
  const int lr = lane & 15;
  const int lkb = (lane >> 4) * 8;
  const int wr = r0 + wave * 16;

  u16x8_t araw[4];
  const u16x8_t zv = {0, 0, 0, 0, 0, 0, 0, 0};
  {
    int grow = wr + lr;
    bool ok = grow < M;
    const unsigned short* Ar = A + (size_t)grow * 128 + lkb;
#pragma unroll
    for (int kc = 0; kc < 4; ++kc)
      araw[kc] = ok ? *reinterpret_cast<const u16x8_t*>(Ar + kc * 32) : zv;
  }
  __syncthreads();  // Bl (and scl/shl) ready

  if (IN_BN) {
#pragma unroll
    for (int kc = 0; kc < 4; ++kc) {
#pragma unroll
      for (int j = 0; j < 8; ++j) {
        int c = kc * 32 + lkb + j;
        araw[kc][j] = f2bf(fmaxf(bf2f(araw[kc][j]) * scl[c] + shl[c], 0.f));
      }
    }
  }

  f32x4_t acc[8];
  f32x4_t zero = {0.f, 0.f, 0.f, 0.f};
#pragma unroll
  for (int i = 0; i < 8; ++i) acc[i] = zero;

#pragma unroll
  for (int kc = 0; kc < 4; ++kc) {
    bf16x8_t af = __builtin_bit_cast(bf16x8_t, araw[kc]);
#pragma unroll
    for (int nt = 0; nt < 8; ++nt) {
      bf16x8_t bf = __builtin_bit_cast(bf16x8_t,
          *reinterpret_cast<const u16x8_t*>(&Bl[nt * 16 + lr][kc * 32 + lkb]));
      acc[nt] = __builtin_amdgcn_mfma_f32_16x16x32_bf16(af, bf, acc[nt], 0, 0, 0);
    }
  }

  const int g = lane >> 4;
#pragma unroll
  for (int nt = 0; nt < 8; ++nt) {
    int col = nt * 16 + lr;
    float bv = bias[col];
    float s4 = 0.f, q4 = 0.f;
#pragma unroll
    for (int j = 0; j < 4; ++j) {
      int gr = wr + g * 4 + j;
      float v = acc[nt][j] + bv;
      if (OUT_RELU) v = fmaxf(v, 0.f);
      if (gr < M) {
        Y[(size_t)gr * 128 + col] = f2bf(v);
        if (STATS) { s4 += v; q4 += v * v; }
      }
    }
    if (STATS) {
      s4 += __shfl_xor(s4, 16);
      s4 += __shfl_xor(s4, 32);
      q4 += __shfl_xor(q4, 16);
      q4 += __shfl_xor(q4, 32);
      if (lane < 16) { atomicAdd(&cs[col], s4); atomicAdd(&cq[col], q4); }
    }
  }
  if (STATS) {
    __syncthreads();
    if (tid < 128) {
      atomicAdd(&osum[tid], cs[tid]);
      atomicAdd(&osq[tid], cq[tid]);
    }
  }
}

// ---------------- fused pair: Y = (relu(A@W1+b1)) @ W2 + b2, + stats ---------
// 512 threads, 8 waves, 16 rows/wave; Al rows wave-local across phases.
__global__ __launch_bounds__(512) void k_mm2x(
    const unsigned short* __restrict__ A,
    const unsigned short* __restrict__ BT1, const float* __restrict__ bias1,
    const unsigned short* __restrict__ BT2, const float* __restrict__ bias2,
    unsigned short* __restrict__ Y, float* __restrict__ osum, float* __restrict__ osq,
    int M) {
  __shared__ __attribute__((aligned(16))) unsigned short Al[128][136];  // Y1
  __shared__ __attribute__((aligned(16))) unsigned short Bl[128][136];  // W1, then W2
  __shared__ float cs[128], cq[128];
  const int tid = threadIdx.x;
  const int r0 = blockIdx.x * 128;
  const int trow = tid >> 4;
  const int tch = (tid & 15) * 8;

#pragma unroll
  for (int pass = 0; pass < 4; ++pass) {
    int n = pass * 32 + trow;
    *reinterpret_cast<u16x8_t*>(&Bl[n][tch]) =
        *reinterpret_cast<const u16x8_t*>(&BT1[(size_t)n * 128 + tch]);
  }
  if (tid < 128) { cs[tid] = 0.f; cq[tid] = 0.f; }

  const int wave = tid >> 6;
  const int lane = tid & 63;
  const int lr = lane & 15;
  const int lkb = (lane >> 4) * 8;
  const int wr = r0 + wave * 16;
  const int g = lane >> 4;

  u16x8_t araw[4];
  const u16x8_t zv = {0, 0, 0, 0, 0, 0, 0, 0};
  {
    int grow = wr + lr;
    bool ok = grow < M;
    const unsigned short* Ar = A + (size_t)grow * 128 + lkb;
#pragma unroll
    for (int kc = 0; kc < 4; ++kc)
      araw[kc] = ok ? *reinterpret_cast<const u16x8_t*>(Ar + kc * 32) : zv;
  }
  __syncthreads();  // Bl ready

  f32x4_t acc[8];
  f32x4_t zero = {0.f, 0.f, 0.f, 0.f};
#pragma unroll
  for (int i = 0; i < 8; ++i) acc[i] = zero;

  // GEMM1
#pragma unroll
  for (int kc = 0; kc < 4; ++kc) {
    bf16x8_t af = __builtin_bit_cast(bf16x8_t, araw[kc]);
#pragma unroll
    for (int nt = 0; nt < 8; ++nt) {
      bf16x8_t bf = __builtin_bit_cast(bf16x8_t,
          *reinterpret_cast<const u16x8_t*>(&Bl[nt * 16 + lr][kc * 32 + lkb]));
      acc[nt] = __builtin_amdgcn_mfma_f32_16x16x32_bf16(af, bf, acc[nt], 0, 0, 0);
    }
  }
  __syncthreads();  // all waves done reading Bl(W1)

  // W2 -> Bl
#pragma unroll
  for (int pass = 0; pass < 4; ++pass) {
    int n = pass * 32 + trow;
    *reinterpret_cast<u16x8_t*>(&Bl[n][tch]) =
        *reinterpret_cast<const u16x8_t*>(&BT2[(size_t)n * 128 + tch]);
  }
  // Y1 = relu(acc + b1) -> Al (wave-local rows)
#pragma unroll
  for (int nt = 0; nt < 8; ++nt) {
    int col = nt * 16 + lr;
    float bv = bias1[col];
#pragma unroll
    for (int j = 0; j < 4; ++j)
      Al[wave * 16 + g * 4 + j][col] = f2bf(fmaxf(acc[nt][j] + bv, 0.f));
  }
  __syncthreads();  // Bl(W2) ready

  // GEMM2
#pragma unroll
  for (int kc = 0; kc < 4; ++kc)
    araw[kc] = *reinterpret_cast<const u16x8_t*>(&Al[wave * 16 + lr][kc * 32 + lkb]);
#pragma unroll
  for (int i = 0; i < 8; ++i) acc[i] = zero;
#pragma unroll
  for (int kc = 0; kc < 4; ++kc) {
    bf16x8_t af = __builtin_bit_cast(bf16x8_t, araw[kc]);
#pragma unroll
    for (int nt = 0; nt < 8; ++nt) {
      bf16x8_t bf = __builtin_bit_cast(bf16x8_t,
          *reinterpret_cast<const u16x8_t*>(&Bl[nt * 16 + lr][kc * 32 + lkb]));
      acc[nt] = __builtin_amdgcn_mfma_f32_16x16x32_bf16(af, bf, acc[nt], 0, 0, 0);
    }
  }

  // epilogue + stats
#pragma unroll
  for (int nt = 0; nt < 8; ++nt) {
    int col = nt * 16 + lr;
    float bv = bias2[col];
    float s4 = 0.f, q4 = 0.f;
#pragma unroll
    for (int j = 0; j < 4; ++j) {
      int gr = wr + g * 4 + j;
      float v = acc[nt][j] + bv;
      if (gr < M) {
        Y[(size_t)gr * 128 + col] = f2bf(v);
        s4 += v; q4 += v * v;
      }
    }
    s4 += __shfl_xor(s4, 16);
    s4 += __shfl_xor(s4, 32);
    q4 += __shfl_xor(q4, 16);
    q4 += __shfl_xor(q4, 32);
    if (lane < 16) { atomicAdd(&cs[col], s4); atomicAdd(&cq[col], q4); }
  }
  __syncthreads();
  if (tid < 128) {
    atomicAdd(&osum[tid], cs[tid]);
    atomicAdd(&osq[tid], cq[tid]);
  }
}

// ---------------- final: out = relu(bn(Y)) as fp32 ---------------------------
__global__ void k_final(const unsigned short* __restrict__ Y,
                        const float* __restrict__ ssum, const float* __restrict__ ssq,
                        const float* __restrict__ gg, const float* __restrict__ bb,
                        float* __restrict__ out, int total8, int N) {
  __shared__ float scl[128], shl[128];
  const int tid = threadIdx.x;
  if (tid < 128) {
    float inv = 1.f / (float)N;
    float m = ssum[tid] * inv;
    float vv = ssq[tid] * inv - m * m;
    float s = gg[tid] * rsqrtf(vv + 1e-5f);
    scl[tid] = s;
    shl[tid] = bb[tid] - m * s;
  }
  __syncthreads();
  int i = blockIdx.x * 256 + tid;
  if (i >= total8) return;
  int base = i * 8;
  int c = base & 127;
  u16x8_t v = *reinterpret_cast<const u16x8_t*>(&Y[base]);
  float4 o0, o1;
  o0.x = fmaxf(bf2f(v[0]) * scl[c + 0] + shl[c + 0], 0.f);
  o0.y = fmaxf(bf2f(v[1]) * scl[c + 1] + shl[c + 1], 0.f);
  o0.z = fmaxf(bf2f(v[2]) * scl[c + 2] + shl[c + 2], 0.f);
  o0.w = fmaxf(bf2f(v[3]) * scl[c + 3] + shl[c + 3], 0.f);
  o1.x = fmaxf(bf2f(v[4]) * scl[c + 4] + shl[c + 4], 0.f);
  o1.y = fmaxf(bf2f(v[5]) * scl[c + 5] + shl[c + 5], 0.f);
  o1.z = fmaxf(bf2f(v[6]) * scl[c + 6] + shl[c + 6], 0.f);
  o1.w = fmaxf(bf2f(v[7]) * scl[c + 7] + shl[c + 7], 0.f);
  *reinterpret_cast<float4*>(&out[base]) = o0;
  *reinterpret_cast<float4*>(&out[base + 4]) = o1;
}

// ---------------------------------------------------------------------------
extern "C" void kernel_launch(void* const* d_in, const int* in_sizes, int n_in,
                              void* d_out, int out_size, void* d_ws, size_t ws_size,
                              hipStream_t stream) {
  (void)n_in; (void)out_size; (void)ws_size;
  const float* x = (const float*)d_in[0];
  const int* ei = (const int*)d_in[1];
  const float* eps = (const float*)d_in[2];
  const int N = in_sizes[0] / 128;
  const int E = in_sizes[1] / 2;
  const int* src = ei;
  const int* dst = ei + E;

  char* ws = (char*)d_ws;
  size_t off = 0;
  auto alloc = [&](size_t bytes) -> char* {
    char* p = ws + off;
    off += (bytes + 255) & ~(size_t)255;
    return p;
  };
  unsigned* csr_off = (unsigned*)alloc((size_t)N * 4);
  unsigned short* csr_src = (unsigned short*)alloc((size_t)E * 2);
  unsigned* bucket_tot = (unsigned*)alloc(256 * 4);
  unsigned* bucket_base = (unsigned*)alloc(257 * 4);
  unsigned* bucket_fill = (unsigned*)alloc(256 * 4);
  float* stats = (float*)alloc(8 * 128 * 4);   // 4x (sum,sq)
  unsigned short* wT = (unsigned short*)alloc(6 * 128 * 128 * 2);
  unsigned short* xb = (unsigned short*)alloc((size_t)N * 128 * 2);
  unsigned short* B1 = (unsigned short*)alloc((size_t)N * 128 * 2);
  unsigned short* B2 = (unsigned short*)alloc((size_t)N * 128 * 2);
  // ebuf aliases B1: dead once k_build completes, before agg0 writes B1.
  unsigned* ebuf = (unsigned*)B1;

  hipMemsetAsync(bucket_tot, 0, 256 * 4, stream);

  const int NBUCK = (N + 255) >> 8;            // 196 for N=50000 (<= 256)
  const int gA = (N + 3) / 4;
  const int gM = (N + 127) / 128;
  const int gF = ((N * 128 / 8) + 255) / 256;
  const int chunk = (E + 255) / 256;

  k_bcount<<<256, 256, 0, stream>>>(dst, bucket_tot, E, NBUCK);
  k_bscan<<<1, 256, 0, stream>>>(bucket_tot, bucket_base, bucket_fill, stats, NBUCK);
  k_bucket<<<256, 256, 0, stream>>>(src, dst, bucket_fill, ebuf, E, NBUCK, chunk);
  k_build<<<NBUCK, 256, 0, stream>>>(ebuf, bucket_base, csr_off, csr_src, N);
  k_wtx<<<96 + gF, 256, 0, stream>>>((const float*)d_in[3], (const float*)d_in[7],
                                     (const float*)d_in[11], (const float*)d_in[13],
                                     (const float*)d_in[17], (const float*)d_in[19], wT,
                                     x, xb, N * 128 / 8);

  // Layer 0: agg -> mm1(+stats s0) -> mm2(bn0-in, +stats s1)
  k_agg<0><<<gA, 256, 0, stream>>>(xb, x, nullptr, nullptr, nullptr, nullptr,
                                   csr_src, csr_off, eps, B1, N);
  k_mm<false, false, true><<<gM, 512, 0, stream>>>(B1, nullptr, nullptr, nullptr, nullptr,
      wT + 0 * 16384, (const float*)d_in[4], B2, stats + 0, stats + 128, N, N);
  k_mm<true, false, true><<<gM, 512, 0, stream>>>(B2, stats + 0, stats + 128,
      (const float*)d_in[5], (const float*)d_in[6],
      wT + 1 * 16384, (const float*)d_in[8], B1, stats + 256, stats + 384, N, N);

  // Layer 1: agg(bn1-in from s1) -> fused pair (+stats s2)
  k_agg<1><<<gA, 256, 0, stream>>>(B1, nullptr, stats + 256, stats + 384,
                                   (const float*)d_in[9], (const float*)d_in[10],
                                   csr_src, csr_off, eps, B2, N);
  k_mm2x<<<gM, 512, 0, stream>>>(B2, wT + 2 * 16384, (const float*)d_in[12],
      wT + 3 * 16384, (const float*)d_in[14], B1, stats + 512, stats + 640, N);

  // Layer 2: agg(bn2-in from s2) -> fused pair (+stats s3)
  k_agg<1><<<gA, 256, 0, stream>>>(B1, nullptr, stats + 512, stats + 640,
                                   (const float*)d_in[15], (const float*)d_in[16],
                                   csr_src, csr_off, eps, B2, N);
  k_mm2x<<<gM, 512, 0, stream>>>(B2, wT + 4 * 16384, (const float*)d_in[18],
      wT + 5 * 16384, (const float*)d_in[20], B1, stats + 768, stats + 896, N);

  k_final<<<gF, 256, 0, stream>>>(B1, stats + 768, stats + 896,
                                  (const float*)d_in[21], (const float*)d_in[22],
                                  (float*)d_out, N * 128 / 8, N);
}